// Round 4
// baseline (867.960 us; speedup 1.0000x reference)
//
#include <hip/hip_runtime.h>

typedef float floatx4 __attribute__((ext_vector_type(4)));
typedef short short8 __attribute__((ext_vector_type(8)));

#define H 768
#define NMENT 4096
#define TOTALP 131072
#define MAXK 64
#define BM 256
#define BN 256
#define BK 64
#define LDA_S 72            // shorts per A row in LDS: 64 data + 8 pad (conflict-free ds_read_b128)
#define ASZ (BM * LDA_S)    // shorts per A buffer (18432)
#define BSZ (BN * BK)       // shorts per B buffer (16384)
#define NKT (H / BK)        // 12 K-tiles

__device__ __forceinline__ unsigned short f32_to_bf16(float f) {
    unsigned int u = __builtin_bit_cast(unsigned int, f);
    u = u + 0x7FFFu + ((u >> 16) & 1u);   // round-to-nearest-even
    return (unsigned short)(u >> 16);
}

__device__ __forceinline__ short8 pack8(float4 a, float4 b) {
    short8 r;
    r[0] = (short)f32_to_bf16(a.x); r[1] = (short)f32_to_bf16(a.y);
    r[2] = (short)f32_to_bf16(a.z); r[3] = (short)f32_to_bf16(a.w);
    r[4] = (short)f32_to_bf16(b.x); r[5] = (short)f32_to_bf16(b.y);
    r[6] = (short)f32_to_bf16(b.z); r[7] = (short)f32_to_bf16(b.w);
    return r;
}

__device__ __forceinline__ void glds16(const unsigned short* g, unsigned short* l) {
    __builtin_amdgcn_global_load_lds(
        (const __attribute__((address_space(1))) unsigned int*)g,
        (__attribute__((address_space(3))) unsigned int*)l, 16, 0, 0);
}

// K0: W1 [1536 x 768] row-major -> BtA[n][k] = W1[k][n] (k<768), BtB[n][k] = W1[768+k][n], bf16
__global__ void k0_transpose(const float* __restrict__ W1,
                             unsigned short* __restrict__ BtA,
                             unsigned short* __restrict__ BtB) {
    __shared__ float tile[32][33];
    const int k0 = blockIdx.x * 32;
    const int n0 = blockIdx.y * 32;
    const int tx = threadIdx.x;
    const int ty = threadIdx.y;
#pragma unroll
    for (int i = 0; i < 4; ++i)
        tile[ty + i * 8][tx] = W1[(k0 + ty + i * 8) * H + n0 + tx];
    __syncthreads();
    unsigned short* dst = (k0 < H) ? BtA : BtB;
    const int kb = (k0 >= H) ? (k0 - H) : k0;
#pragma unroll
    for (int i = 0; i < 4; ++i) {
        const int n = n0 + ty + i * 8;
        dst[n * H + kb + tx] = f32_to_bf16(tile[tx][ty + i * 8]);
    }
}

// K3: out[n][j] = 0.5*faiss[n][j] for j<64, nota for j==64 (b2 added by nsplit==0 k2 blocks)
__global__ void k3_init_out(const float* __restrict__ faiss,
                            const float* __restrict__ nota,
                            float* __restrict__ out) {
    const int i = blockIdx.x * 256 + threadIdx.x;
    if (i < NMENT * (MAXK + 1)) {
        const int n = i / (MAXK + 1);
        const int j = i - n * (MAXK + 1);
        out[i] = (j < MAXK) ? 0.5f * faiss[n * MAXK + j] : nota[0];
    }
}

// Core GEMM: C[t0..t0+255][n0..n0+255] = A(rows, fp32, cast bf16) @ Bt^T (bf16 [n][k])
// m201-style phase-split schedule (T3+T4+T5), reg-staged A (T14):
//  8 waves (2m x 4n), 128x64 per-wave tile, double-buffered LDS (140KB, 1 block/CU).
//  Per K-tile, 4 phases: {stage-piece || ds_read frags -> s_barrier -> lgkmcnt(0) ->
//  sched_barrier(0) -> setprio(1) 16xMFMA setprio(0) -> s_barrier}.
//  Staging pieces: p0 = A float4 loads (regs), p1 = B glds x4 into buf^1,
//  p3 = pack+ds_write A (compiler emits a counted vmcnt for the A-reg dep, leaving
//  the B glds in flight). ONE __syncthreads per K-tile at p3 end: its vmcnt(0)
//  drain covers loads issued 2-3 phases (~800cy of MFMA) earlier.
//  NOTE all barriers are block-uniform (loop bounds compile-time, `stage` depends
//  only on t) -> no divergent-barrier hazard. Correctness does not depend on the
//  scheduling pins; compiler-tracked deps + the boundary __syncthreads suffice.
// MODE 0: epilogue writes M = acc + b1  (outp = M, w2s holds b1 chunk)
// MODE 1: epilogue: h = acc + M[mention], relu, dot W2-chunk, reduce, atomicAdd to out
template<int MODE>
__global__ __launch_bounds__(512, 2)
void gemm_core(const float* __restrict__ A, const unsigned short* __restrict__ Bt,
               const float* __restrict__ M, const float* __restrict__ W2,
               const float* __restrict__ b2, const int* __restrict__ mention_idx,
               const int* __restrict__ col_idx, const float* __restrict__ b1,
               float* __restrict__ outp) {
    __shared__ unsigned short ldsA[2 * ASZ];   // 73728 B
    __shared__ unsigned short ldsB[2 * BSZ];   // 65536 B
    __shared__ float w2s[BN];                  // 1024 B  (total 140288 B -> 1 block/CU)
    // scoreBuf (MODE 1, BM*4 floats = 4KB) aliases ldsA: only used after final K-tile sync

    const int bid = blockIdx.x;
    int t_tile, nsplit;
    if (MODE == 1) {
        // groups of 24 = 8 t-tiles x 3 nsplits; 24%8==0 so a t-tile's 3 n-splits share
        // bid%8 -> same XCD; 8 A-panels (6MB fp32) mostly L2/L3-resident per group
        const int g = bid / 24, rr = bid % 24;
        t_tile = g * 8 + (rr & 7);
        nsplit = rr >> 3;
    } else {
        t_tile = bid % 16;
        nsplit = bid / 16;
    }
    const int t0 = t_tile * BM;
    const int n0 = nsplit * BN;

    const int tid = threadIdx.x;
    const int lane = tid & 63;
    const int w = tid >> 6;            // 8 waves: 2x4 grid of 128x64 wave tiles
    const int wm = w >> 2, wn = w & 3; // wm 0..1, wn 0..3
    const int l15 = lane & 15, quad = lane >> 4;

    if (tid < BN) w2s[tid] = (MODE == 1) ? W2[n0 + tid] : b1[n0 + tid];

    floatx4 acc[8][4];
#pragma unroll
    for (int mf = 0; mf < 8; ++mf)
#pragma unroll
        for (int ni = 0; ni < 4; ++ni)
            acc[mf][ni] = floatx4{0.f, 0.f, 0.f, 0.f};

    // A staging map: 2 threads per row, 32 floats (128B) each
    const int arow = tid >> 1;         // 0..255
    const int aseg = tid & 1;
    const float* agp = A + (size_t)(t0 + arow) * H + aseg * 32;
    const int aoff = arow * LDA_S + aseg * 32;

    short8 a[4], b[4];

#define READ_A(LA, MH, KS)                                                                \
    _Pragma("unroll")                                                                     \
    for (int mi = 0; mi < 4; ++mi)                                                        \
        a[mi] = *(const short8*)&(LA)[(wm * 128 + ((MH) * 4 + mi) * 16 + l15) * LDA_S + (KS) * 32 + quad * 8];

#define READ_B(LB, KS)                                                                    \
    _Pragma("unroll")                                                                     \
    for (int ni = 0; ni < 4; ++ni) {                                                      \
        const int nr = wn * 64 + ni * 16 + l15;                                           \
        const int slot = (quad + (KS) * 4) ^ (nr & 7);                                    \
        b[ni] = *(const short8*)&(LB)[nr * BK + slot * 8];                                \
    }

#define MFMA16(MH)                                                                        \
    _Pragma("unroll")                                                                     \
    for (int mi = 0; mi < 4; ++mi)                                                        \
        _Pragma("unroll")                                                                 \
        for (int ni = 0; ni < 4; ++ni)                                                    \
            acc[(MH) * 4 + mi][ni] =                                                      \
                __builtin_amdgcn_mfma_f32_16x16x32_bf16(a[mi], b[ni], acc[(MH) * 4 + mi][ni], 0, 0, 0);

#define ALIGN_PIN()                                                                       \
    __builtin_amdgcn_s_barrier();                                                         \
    asm volatile("s_waitcnt lgkmcnt(0)");                                                 \
    __builtin_amdgcn_sched_barrier(0);

#define STAGE_B(SB, KC)                                                                   \
    _Pragma("unroll")                                                                     \
    for (int i = 0; i < 4; ++i) {                                                         \
        const int br = w * 32 + i * 8;          /* wave-uniform base row */               \
        const int r = br + (lane >> 3);                                                   \
        const int cd = (lane & 7) ^ (r & 7);    /* XOR swizzle: slot holds chunk c^(row&7) */ \
        glds16(Bt + (size_t)(n0 + r) * H + (KC) + cd * 8, (SB) + br * BK);                \
    }

    // ---- prologue: stage K-tile 0 into buffer 0 ----
    {
        const float4 v0 = *(const float4*)(agp);      const float4 v1 = *(const float4*)(agp + 4);
        const float4 v2 = *(const float4*)(agp + 8);  const float4 v3 = *(const float4*)(agp + 12);
        const float4 v4 = *(const float4*)(agp + 16); const float4 v5 = *(const float4*)(agp + 20);
        const float4 v6 = *(const float4*)(agp + 24); const float4 v7 = *(const float4*)(agp + 28);
        STAGE_B(ldsB, 0);
        *(short8*)(&ldsA[aoff])      = pack8(v0, v1);
        *(short8*)(&ldsA[aoff + 8])  = pack8(v2, v3);
        *(short8*)(&ldsA[aoff + 16]) = pack8(v4, v5);
        *(short8*)(&ldsA[aoff + 24]) = pack8(v6, v7);
        __syncthreads();
    }

    int cur = 0;
    for (int t = 0; t < NKT; ++t) {
        const unsigned short* lA = ldsA + cur * ASZ;
        const unsigned short* lB = ldsB + cur * BSZ;
        unsigned short* sA = ldsA + (cur ^ 1) * ASZ;
        unsigned short* sB = ldsB + (cur ^ 1) * BSZ;
        const int kn = (t + 1) * BK;
        const bool stage = (t < NKT - 1);   // block-uniform
        float4 v0, v1, v2, v3, v4, v5, v6, v7;

        // ---- phase 0: issue next-tile A loads; MFMA quadrant (mh=0, ks=0) ----
        if (stage) {
            v0 = *(const float4*)(agp + kn);      v1 = *(const float4*)(agp + kn + 4);
            v2 = *(const float4*)(agp + kn + 8);  v3 = *(const float4*)(agp + kn + 12);
            v4 = *(const float4*)(agp + kn + 16); v5 = *(const float4*)(agp + kn + 20);
            v6 = *(const float4*)(agp + kn + 24); v7 = *(const float4*)(agp + kn + 28);
        }
        READ_B(lB, 0);
        READ_A(lA, 0, 0);
        ALIGN_PIN();
        __builtin_amdgcn_s_setprio(1);
        MFMA16(0);
        __builtin_amdgcn_s_setprio(0);
        __builtin_amdgcn_s_barrier();

        // ---- phase 1: issue next-tile B glds; MFMA quadrant (mh=1, ks=0), b reused ----
        if (stage) { STAGE_B(sB, kn); }
        READ_A(lA, 1, 0);
        ALIGN_PIN();
        __builtin_amdgcn_s_setprio(1);
        MFMA16(1);
        __builtin_amdgcn_s_setprio(0);
        __builtin_amdgcn_s_barrier();

        // ---- phase 2: MFMA quadrant (mh=0, ks=1) ----
        READ_B(lB, 1);
        READ_A(lA, 0, 1);
        ALIGN_PIN();
        __builtin_amdgcn_s_setprio(1);
        MFMA16(0);
        __builtin_amdgcn_s_setprio(0);
        __builtin_amdgcn_s_barrier();

        // ---- phase 3: pack+write A (counted vmcnt leaves B glds in flight);
        //              MFMA quadrant (mh=1, ks=1); boundary sync drains all ----
        if (stage) {
            *(short8*)(&sA[aoff])      = pack8(v0, v1);
            *(short8*)(&sA[aoff + 8])  = pack8(v2, v3);
            *(short8*)(&sA[aoff + 16]) = pack8(v4, v5);
            *(short8*)(&sA[aoff + 24]) = pack8(v6, v7);
        }
        READ_A(lA, 1, 1);
        ALIGN_PIN();
        __builtin_amdgcn_s_setprio(1);
        MFMA16(1);
        __builtin_amdgcn_s_setprio(0);
        __syncthreads();   // vmcnt(0)+lgkmcnt(0)+fence: B glds (issued 2 phases ago) and
                           // A ds_writes visible to all before next tile reads buf^1
        cur ^= 1;
    }

#undef READ_A
#undef READ_B
#undef MFMA16
#undef ALIGN_PIN
#undef STAGE_B

    if (MODE == 0) {
        // write M = acc + b1
#pragma unroll
        for (int mf = 0; mf < 8; ++mf)
#pragma unroll
            for (int ni = 0; ni < 4; ++ni) {
                const int nl = wn * 64 + ni * 16 + l15;
                const float bv = w2s[nl];
#pragma unroll
                for (int r = 0; r < 4; ++r) {
                    const int row = t0 + wm * 128 + mf * 16 + quad * 4 + r;
                    outp[(size_t)row * H + n0 + nl] = acc[mf][ni][r] + bv;
                }
            }
    } else {
        // h = acc + M[mention]; relu; dot with W2 chunk; reduce; atomicAdd
        float* scoreBuf = (float*)ldsA;   // ldsA free after final K-tile sync
#pragma unroll
        for (int mf = 0; mf < 8; ++mf) {
#pragma unroll
            for (int r = 0; r < 4; ++r) {
                const int rl = wm * 128 + mf * 16 + quad * 4 + r;
                const int m = mention_idx[t0 + rl];
                const float* Mrow = M + (size_t)m * H + n0;
                float s = 0.f;
#pragma unroll
                for (int ni = 0; ni < 4; ++ni) {
                    const int nl = wn * 64 + ni * 16 + l15;
                    const float v = acc[mf][ni][r] + Mrow[nl];
                    s = fmaf(fmaxf(v, 0.f), w2s[nl], s);
                }
                s += __shfl_xor(s, 1, 64);
                s += __shfl_xor(s, 2, 64);
                s += __shfl_xor(s, 4, 64);
                s += __shfl_xor(s, 8, 64);
                if (l15 == 0) scoreBuf[rl * 4 + wn] = s;
            }
        }
        __syncthreads();
        if (tid < BM) {
            const int t = t0 + tid;
            float tot = scoreBuf[tid * 4] + scoreBuf[tid * 4 + 1] +
                        scoreBuf[tid * 4 + 2] + scoreBuf[tid * 4 + 3];
            if (nsplit == 0) tot += b2[0];
            atomicAdd(&outp[(size_t)mention_idx[t] * (MAXK + 1) + col_idx[t]], tot);
        }
    }
}

extern "C" void kernel_launch(void* const* d_in, const int* in_sizes, int n_in,
                              void* d_out, int out_size, void* d_ws, size_t ws_size,
                              hipStream_t stream) {
    const float* ment  = (const float*)d_in[0];
    const float* cand  = (const float*)d_in[1];
    const float* W1    = (const float*)d_in[2];
    const float* b1    = (const float*)d_in[3];
    const float* W2    = (const float*)d_in[4];
    const float* b2    = (const float*)d_in[5];
    const float* faiss = (const float*)d_in[6];
    const float* nota  = (const float*)d_in[7];
    const int* mention_idx = (const int*)d_in[8];
    const int* col_idx = (const int*)d_in[9];
    float* out = (float*)d_out;

    // ws: BtA bf16 [768*768] | BtB bf16 [768*768] | M fp32 [4096*768]  (~14.9 MB)
    unsigned short* BtA = (unsigned short*)d_ws;
    unsigned short* BtB = BtA + H * H;
    float* M = (float*)(BtB + H * H);

    k0_transpose<<<dim3(48, 24), dim3(32, 8), 0, stream>>>(W1, BtA, BtB);
    k3_init_out<<<(NMENT * (MAXK + 1) + 255) / 256, 256, 0, stream>>>(faiss, nota, out);
    // K1: M[4096x768] = ment @ W1a + b1 : 16 t-tiles x 3 n-splits
    gemm_core<0><<<48, 512, 0, stream>>>(ment, BtA, nullptr, nullptr, nullptr,
                                         nullptr, nullptr, b1, M);
    // K2: 512 t-tiles x 3 n-splits, XCD-grouped (24-block groups)
    gemm_core<1><<<1536, 512, 0, stream>>>(cand, BtB, M, W2, b2,
                                           mention_idx, col_idx, nullptr, out);
}